// Round 19
// baseline (275.876 us; speedup 1.0000x reference)
//
#include <hip/hip_runtime.h>
#include <stdint.h>

// ---------- types / helpers ----------
typedef __attribute__((ext_vector_type(8))) short short8;   // 8 x bf16 (4 VGPRs)
typedef __attribute__((ext_vector_type(4))) float f32x4;

typedef const void __attribute__((address_space(1)))* gas1_t;
typedef void __attribute__((address_space(3)))* las3_t;
#define GLL16(g, l) __builtin_amdgcn_global_load_lds((gas1_t)(const void*)(g), (las3_t)(void*)(l), 16, 0, 0)

__device__ __forceinline__ unsigned short f2bf(float x){
  union { float f; unsigned u; } c; c.f = x;
  return (unsigned short)((c.u + 0x7fffu + ((c.u >> 16) & 1u)) >> 16);
}
__device__ __forceinline__ float bf2f(unsigned short u){
  union { unsigned u; float f; } c; c.u = ((unsigned)u) << 16; return c.f;
}
__device__ __forceinline__ unsigned cvtpk(float lo, float hi){
  unsigned r;
  asm("v_cvt_pk_bf16_f32 %0, %1, %2" : "=v"(r) : "v"(lo), "v"(hi));
  return r;
}

constexpr int Bc = 4, Lc = 2048, Dc = 768, Hc = 12, HDc = 64, Ic = 3072;
constexpr int Mrows = Bc * Lc;        // 8192
constexpr int N3 = 3 * Dc;            // 2304

// ---------- weight transpose fp32[K][N] -> bf16[N][K] ----------
__global__ void transpose_w(const float* __restrict__ W, unsigned short* __restrict__ Wt, int K, int N){
  __shared__ float t[32][33];
  int n0 = blockIdx.x * 32, k0 = blockIdx.y * 32;
  int tx = threadIdx.x, ty = threadIdx.y;   // (32,8)
  #pragma unroll
  for (int j = 0; j < 4; ++j)
    t[ty + 8*j][tx] = W[(size_t)(k0 + ty + 8*j) * N + n0 + tx];
  __syncthreads();
  #pragma unroll
  for (int j = 0; j < 4; ++j)
    Wt[(size_t)(n0 + ty + 8*j) * K + k0 + tx] = f2bf(t[tx][ty + 8*j]);
}

// ---------- V transpose: vt[bh][d=64][L=2048] from qkv ----------
__global__ void transpose_v(const unsigned short* __restrict__ qkv, unsigned short* __restrict__ vt){
  __shared__ unsigned short t[32][33];
  int l0 = blockIdx.x * 32, d0 = blockIdx.y * 32;
  int bh = blockIdx.z; int b = bh / Hc, h = bh - b * Hc;
  int tx = threadIdx.x, ty = threadIdx.y;   // (32,8)
  const unsigned short* src = qkv + (size_t)b * Lc * N3 + h * 192 + 128;
  #pragma unroll
  for (int j = 0; j < 4; ++j)
    t[ty + 8*j][tx] = src[(size_t)(l0 + ty + 8*j) * N3 + d0 + tx];
  __syncthreads();
  unsigned short* dst = vt + (size_t)bh * 64 * Lc;
  #pragma unroll
  for (int j = 0; j < 4; ++j)
    dst[(size_t)(d0 + ty + 8*j) * Lc + l0 + tx] = t[tx][ty + 8*j];
}

// ---------- LayerNorm: fp32 row (768) -> bf16 row ----------
__global__ __launch_bounds__(256) void ln_kernel(const float* __restrict__ x, const float* __restrict__ g,
                                                 const float* __restrict__ bta, unsigned short* __restrict__ out){
  int row = blockIdx.x, tid = threadIdx.x;
  const float* xr = x + (size_t)row * 768;
  float v0 = xr[tid], v1 = xr[tid + 256], v2 = xr[tid + 512];
  float s = v0 + v1 + v2;
  float ss = v0*v0 + v1*v1 + v2*v2;
  #pragma unroll
  for (int o = 32; o > 0; o >>= 1){ s += __shfl_xor(s, o); ss += __shfl_xor(ss, o); }
  __shared__ float red[8];
  int w = tid >> 6;
  if ((tid & 63) == 0){ red[w] = s; red[4 + w] = ss; }
  __syncthreads();
  s  = red[0] + red[1] + red[2] + red[3];
  ss = red[4] + red[5] + red[6] + red[7];
  float mu  = s * (1.f / 768.f);
  float var = ss * (1.f / 768.f) - mu * mu;
  float rs  = rsqrtf(var + 1e-5f);
  unsigned short* orow = out + (size_t)row * 768;
  orow[tid]       = f2bf((v0 - mu) * rs * g[tid]       + bta[tid]);
  orow[tid + 256] = f2bf((v1 - mu) * rs * g[tid + 256] + bta[tid + 256]);
  orow[tid + 512] = f2bf((v2 - mu) * rs * g[tid + 512] + bta[tid + 512]);
}

// ---------- LayerNorm: bf16 row (768) -> bf16 row ----------
__global__ __launch_bounds__(256) void ln_kernel_bf(const unsigned short* __restrict__ x, const float* __restrict__ g,
                                                    const float* __restrict__ bta, unsigned short* __restrict__ out){
  int row = blockIdx.x, tid = threadIdx.x;
  const unsigned short* xr = x + (size_t)row * 768;
  float v0 = bf2f(xr[tid]), v1 = bf2f(xr[tid + 256]), v2 = bf2f(xr[tid + 512]);
  float s = v0 + v1 + v2;
  float ss = v0*v0 + v1*v1 + v2*v2;
  #pragma unroll
  for (int o = 32; o > 0; o >>= 1){ s += __shfl_xor(s, o); ss += __shfl_xor(ss, o); }
  __shared__ float red[8];
  int w = tid >> 6;
  if ((tid & 63) == 0){ red[w] = s; red[4 + w] = ss; }
  __syncthreads();
  s  = red[0] + red[1] + red[2] + red[3];
  ss = red[4] + red[5] + red[6] + red[7];
  float mu  = s * (1.f / 768.f);
  float var = ss * (1.f / 768.f) - mu * mu;
  float rs  = rsqrtf(var + 1e-5f);
  unsigned short* orow = out + (size_t)row * 768;
  orow[tid]       = f2bf((v0 - mu) * rs * g[tid]       + bta[tid]);
  orow[tid + 256] = f2bf((v1 - mu) * rs * g[tid + 256] + bta[tid + 256]);
  orow[tid + 512] = f2bf((v2 - mu) * rs * g[tid + 512] + bta[tid + 512]);
}

// ---------- 8-phase GEMM: BM=128, BN=256, BK=64, 512 thr, 8 waves, 64x64/wave ----
// m201-template port for QKV/FF1 (MODE0: bf16 out + bias). Both operands double-
// buffered (96KB, 1 block/CU); __launch_bounds__(512,1) -> full 256-VGPR budget
// (prior 8-phase failures were the (512,2) 128-VGPR cap spilling acc).
// Tile parity: even K-tile -> buf0, odd -> buf1. Per iteration (2 K-tiles), 8
// phases; each phase: {ds_read quadrant frags | stage into dead region} -> 8 MFMA
// (setprio) -> barrier. vmcnt(6)+barrier at ph0/ph4 only (6-load groups).
__global__ __launch_bounds__(512, 1) void gemm8p(
    const unsigned short* __restrict__ A, const unsigned short* __restrict__ Bt,
    const float* __restrict__ bias, unsigned short* __restrict__ outp,
    int Kdim, int Ndim)
{
  __shared__ __align__(16) unsigned short Als[2][128 * 64];   // 32 KB
  __shared__ __align__(16) unsigned short Bls[2][256 * 64];   // 64 KB
  int tid = threadIdx.x, w = tid >> 6, lane = tid & 63;
  int g = lane >> 4, r16 = lane & 15;
  int wm = w >> 2, wn = w & 3;                 // 2m x 4n, per-wave 64x64

  int nwg = gridDim.x * gridDim.y;
  int flat = blockIdx.y * gridDim.x + blockIdx.x;
  int cpx = nwg >> 3;
  int swz = (flat & 7) * cpx + (flat >> 3);
  int bx = swz % gridDim.x, by = swz / gridDim.x;
  int m0 = by * 128, n0 = bx * 256;

  f32x4 acc[4][4];
  #pragma unroll
  for (int m = 0; m < 4; ++m)
    #pragma unroll
    for (int n = 0; n < 4; ++n) acc[m][n] = f32x4{0.f, 0.f, 0.f, 0.f};

  int lrow = lane >> 3;
  int gsw8 = ((lane & 7) ^ lrow) * 8;
  auto stageA = [&](int buf, int kt){          // 2 GLL16/thread
    int k0 = kt * 64;
    #pragma unroll
    for (int i = 0; i < 2; ++i){
      int c = w * 2 + i;
      int row = c * 8 + lrow;
      GLL16(A + (size_t)(m0 + row) * Kdim + k0 + gsw8, &Als[buf][c * 512]);
    }
  };
  auto stageB = [&](int buf, int kt){          // 4 GLL16/thread
    int k0 = kt * 64;
    #pragma unroll
    for (int i = 0; i < 4; ++i){
      int c = w * 4 + i;
      int row = c * 8 + lrow;
      GLL16(Bt + (size_t)(n0 + row) * Kdim + k0 + gsw8, &Bls[buf][c * 512]);
    }
  };
  auto ldA = [&](int buf, int m, int ks) -> short8 {
    int r = wm * 64 + m * 16 + r16;
    return *(const short8*)&Als[buf][r * 64 + (((ks*4 + g) ^ (r & 7)) << 3)];
  };
  auto ldB = [&](int buf, int n, int ks) -> short8 {
    int r = wn * 64 + n * 16 + r16;
    return *(const short8*)&Bls[buf][r * 64 + (((ks*4 + g) ^ (r & 7)) << 3)];
  };

#define QMM(AF, BF, MB, NB) { \
  __builtin_amdgcn_s_setprio(1); \
  _Pragma("unroll") for (int m_ = 0; m_ < 2; ++m_) \
  _Pragma("unroll") for (int n_ = 0; n_ < 2; ++n_) \
  _Pragma("unroll") for (int k_ = 0; k_ < 2; ++k_) \
    acc[(MB)+m_][(NB)+n_] = __builtin_amdgcn_mfma_f32_16x16x32_bf16(AF[m_][k_], BF[n_][k_], acc[(MB)+m_][(NB)+n_], 0, 0, 0); \
  __builtin_amdgcn_s_setprio(0); }
#define BAR() __builtin_amdgcn_s_barrier()

  int NK = Kdim >> 6;            // even for K=768 (12) and 3072 (48)
  int NITER = NK >> 1;

  // prologue: group0 = tile0 (6 loads), group1 = tile1 (6 loads)
  stageB(0, 0); stageA(0, 0);
  stageB(1, 1); stageA(1, 1);

  short8 af[2][2], bf0[2][2], bf1[2][2];

  for (int it = 0; it < NITER; ++it){
    int t = 2 * it;
    bool more = (t + 2 < NK);
    bool last = (it == NITER - 1);

    // ---- ph0: tile t (buf0) q(m0-1, n0-1) ----
    asm volatile("s_waitcnt vmcnt(6)" ::: "memory");   // group t landed
    BAR();                                             // all waves' loads landed
    #pragma unroll
    for (int k_ = 0; k_ < 2; ++k_){
      af[0][k_] = ldA(0, 0, k_); af[1][k_] = ldA(0, 1, k_);
      bf0[0][k_] = ldB(0, 0, k_); bf0[1][k_] = ldB(0, 1, k_);
    }
    QMM(af, bf0, 0, 0);
    BAR();
    // ---- ph1: q(m0-1, n2-3) ----
    #pragma unroll
    for (int k_ = 0; k_ < 2; ++k_){ bf1[0][k_] = ldB(0, 2, k_); bf1[1][k_] = ldB(0, 3, k_); }
    QMM(af, bf1, 0, 2);
    BAR();                                             // B(t) dead after this
    // ---- ph2: q(m2-3, n2-3) | stage B(t+2)->buf0 ----
    #pragma unroll
    for (int k_ = 0; k_ < 2; ++k_){ af[0][k_] = ldA(0, 2, k_); af[1][k_] = ldA(0, 3, k_); }
    if (more) stageB(0, t + 2);
    QMM(af, bf1, 2, 2);
    BAR();                                             // A(t) dead after this
    // ---- ph3: q(m2-3, n0-1) | stage A(t+2)->buf0 ----
    if (more) stageA(0, t + 2);
    QMM(af, bf0, 2, 0);
    BAR();

    // ---- ph4: tile t+1 (buf1) q(m0-1, n0-1) ----
    if (last) { asm volatile("s_waitcnt vmcnt(0)" ::: "memory"); }
    else      { asm volatile("s_waitcnt vmcnt(6)" ::: "memory"); }   // group t+1 landed
    BAR();
    #pragma unroll
    for (int k_ = 0; k_ < 2; ++k_){
      af[0][k_] = ldA(1, 0, k_); af[1][k_] = ldA(1, 1, k_);
      bf0[0][k_] = ldB(1, 0, k_); bf0[1][k_] = ldB(1, 1, k_);
    }
    QMM(af, bf0, 0, 0);
    BAR();
    // ---- ph5: q(m0-1, n2-3) ----
    #pragma unroll
    for (int k_ = 0; k_ < 2; ++k_){ bf1[0][k_] = ldB(1, 2, k_); bf1[1][k_] = ldB(1, 3, k_); }
    QMM(af, bf1, 0, 2);
    BAR();
    // ---- ph6: q(m2-3, n2-3) | stage B(t+3)->buf1 ----
    #pragma unroll
    for (int k_ = 0; k_ < 2; ++k_){ af[0][k_] = ldA(1, 2, k_); af[1][k_] = ldA(1, 3, k_); }
    if (more) stageB(1, t + 3);
    QMM(af, bf1, 2, 2);
    BAR();
    // ---- ph7: q(m2-3, n0-1) | stage A(t+3)->buf1 ----
    if (more) stageA(1, t + 3);
    QMM(af, bf0, 2, 0);
    BAR();
  }

#undef QMM
#undef BAR

  #pragma unroll
  for (int n = 0; n < 4; ++n){
    int col = n0 + wn * 64 + n * 16 + r16;
    float bv = bias[col];
    #pragma unroll
    for (int m = 0; m < 4; ++m){
      #pragma unroll
      for (int j = 0; j < 4; ++j){
        int rowg = m0 + wm * 64 + m * 16 + g * 4 + j;
        outp[(size_t)rowg * Ndim + col] = f2bf(acc[m][n][j] + bv);
      }
    }
  }
}

// ---------- small GEMM: BM=64, BN=128, BK=64, 8 waves (2m x 4n), per-wave 32x32 ----
template<int MODE>
__global__ __launch_bounds__(512, 6) void gemm64(
    const unsigned short* __restrict__ A, const unsigned short* __restrict__ Bt,
    const float* __restrict__ bias, const void* __restrict__ res,
    void* __restrict__ outp, int Kdim, int Ndim)
{
  __shared__ __align__(16) unsigned short Als[2][64 * 64];    // 16 KB
  __shared__ __align__(16) unsigned short Bls[2][128 * 64];   // 32 KB
  int tid = threadIdx.x, w = tid >> 6, lane = tid & 63;
  int g = lane >> 4, r16 = lane & 15;
  int wm = w >> 2, wn = w & 3;                 // 2m x 4n waves, per-wave 32x32

  int nwg = gridDim.x * gridDim.y;
  int flat = blockIdx.y * gridDim.x + blockIdx.x;
  int cpx = nwg >> 3;
  int swz = (flat & 7) * cpx + (flat >> 3);
  int bx = swz % gridDim.x, by = swz / gridDim.x;
  int m0 = by * 64, n0 = bx * 128;

  f32x4 acc[2][2];
  #pragma unroll
  for (int m = 0; m < 2; ++m)
    #pragma unroll
    for (int n = 0; n < 2; ++n) acc[m][n] = f32x4{0.f, 0.f, 0.f, 0.f};

  int lrow = lane >> 3;                          // row within 8-row chunk
  int gsw8 = ((lane & 7) ^ lrow) * 8;            // inverse-swizzled source granule*8
  auto stage = [&](int buf, int kt){             // 3 GLL16/thread (1 A + 2 B)
    int k0 = kt * 64;
    {
      int c = w;                                 // A: 8 chunks of 8 rows
      int row = c * 8 + lrow;
      GLL16(A + (size_t)(m0 + row) * Kdim + k0 + gsw8, &Als[buf][c * 512]);
    }
    #pragma unroll
    for (int i = 0; i < 2; ++i){                 // B: 16 chunks of 8 rows
      int c = w * 2 + i;
      int row = c * 8 + lrow;
      GLL16(Bt + (size_t)(n0 + row) * Kdim + k0 + gsw8, &Bls[buf][c * 512]);
    }
  };

  int nk = Kdim >> 6;
  stage(0, 0);                                   // 3 loads in flight
  int cur = 0;
  for (int kt = 0; kt < nk; ++kt){
    __builtin_amdgcn_s_barrier();                // buf cur^1 free
    if (kt + 1 < nk){
      stage(cur ^ 1, kt + 1);                    // +3 loads (6 in flight)
      asm volatile("s_waitcnt vmcnt(3)" ::: "memory");  // oldest 3 (tile kt) landed
    } else {
      asm volatile("s_waitcnt vmcnt(0)" ::: "memory");
    }
    __builtin_amdgcn_s_barrier();                // tile kt visible

    #pragma unroll
    for (int ks = 0; ks < 2; ++ks){
      short8 af[2], bfv[2];
      #pragma unroll
      for (int m = 0; m < 2; ++m){
        int r = wm * 32 + m * 16 + r16;
        af[m] = *(const short8*)&Als[cur][r * 64 + (((ks*4 + g) ^ (r & 7)) << 3)];
      }
      #pragma unroll
      for (int n = 0; n < 2; ++n){
        int r = wn * 32 + n * 16 + r16;
        bfv[n] = *(const short8*)&Bls[cur][r * 64 + (((ks*4 + g) ^ (r & 7)) << 3)];
      }
      #pragma unroll
      for (int m = 0; m < 2; ++m)
        #pragma unroll
        for (int n = 0; n < 2; ++n)
          acc[m][n] = __builtin_amdgcn_mfma_f32_16x16x32_bf16(af[m], bfv[n], acc[m][n], 0, 0, 0);
    }
    cur ^= 1;
  }

  #pragma unroll
  for (int n = 0; n < 2; ++n){
    int col = n0 + wn * 32 + n * 16 + r16;
    float bv = bias[col];
    #pragma unroll
    for (int m = 0; m < 2; ++m){
      #pragma unroll
      for (int j = 0; j < 4; ++j){
        int rowg = m0 + wm * 32 + m * 16 + g * 4 + j;
        size_t idx = (size_t)rowg * Ndim + col;
        float v = acc[m][n][j] + bv;
        if (MODE == 1){
          ((unsigned short*)outp)[idx] = f2bf(v + ((const float*)res)[idx]);
        } else {
          float ge = 0.5f * v * (1.0f + erff(v * 0.70710678118f));
          ((float*)outp)[idx] = bf2f(((const unsigned short*)res)[idx]) + ge;
        }
      }
    }
  }
}

// ---------- flash attention (causal, scores/64), mq=2: 32 q-rows/wave ----------
__global__ __launch_bounds__(256, 3) void attn_kernel(const unsigned short* __restrict__ qkv,
                                                      const unsigned short* __restrict__ vt,
                                                      unsigned short* __restrict__ attn_out){
  int qt = 15 - blockIdx.y;            // big blocks dispatch first
  int bh = blockIdx.x;
  int b = bh / Hc, h = bh - b * Hc;
  int tid = threadIdx.x, w = tid >> 6, lane = tid & 63;
  int g = lane >> 4, r16 = lane & 15;
  const unsigned short* base  = qkv + (size_t)b * Lc * N3 + h * 192;
  const unsigned short* vbase = vt + (size_t)bh * 64 * Lc;

  __shared__ __align__(16) unsigned short Kls[2][64 * 64];   // 16 KB
  __shared__ __align__(16) unsigned short Vls[2][64 * 64];   // 16 KB
  __shared__ __align__(16) unsigned short Pls[4][32 * 64];   // 16 KB (bf16 P)

  constexpr float SM_SCALE = 0.022542110013890052f;   // log2(e)/64

  int qw = qt * 128 + w * 32;          // wave's 32 q rows
  short8 qf[2][2];
  #pragma unroll
  for (int mq = 0; mq < 2; ++mq)
    #pragma unroll
    for (int dh = 0; dh < 2; ++dh){
      short8 v = *(const short8*)(base + (size_t)(qw + mq*16 + r16) * N3 + dh*32 + g*8);
      union { unsigned u[4]; short8 s8; } r;
      #pragma unroll
      for (int i = 0; i < 4; ++i){
        float lo = bf2f((unsigned short)v[2*i])     * SM_SCALE;
        float hi = bf2f((unsigned short)v[2*i + 1]) * SM_SCALE;
        r.u[i] = cvtpk(lo, hi);
      }
      qf[mq][dh] = r.s8;
    }

  short8 ones;
  #pragma unroll
  for (int i = 0; i < 8; ++i) ones[i] = (short)0x3F80;   // bf16 1.0

  f32x4 o[2][4];
  f32x4 acc_l[2];
  #pragma unroll
  for (int mq = 0; mq < 2; ++mq){
    #pragma unroll
    for (int nd = 0; nd < 4; ++nd) o[mq][nd] = f32x4{0.f, 0.f, 0.f, 0.f};
    acc_l[mq] = f32x4{0.f, 0.f, 0.f, 0.f};
  }

  unsigned short* Pw = &Pls[w][0];

  int lrow = lane >> 3, csw8 = ((lane & 7) ^ lrow) * 8;
  auto stage = [&](int buf, int kt){
    #pragma unroll
    for (int i = 0; i < 2; ++i){
      int r0 = (w * 2 + i) * 8;
      int row = r0 + lrow;
      GLL16(base  + (size_t)(kt*64 + row) * N3 + 64 + csw8, &Kls[buf][r0 * 64]);
      GLL16(vbase + (size_t)row * Lc + kt*64 + csw8,        &Vls[buf][r0 * 64]);
    }
  };

  auto compute_tile = [&](int cur, int kt, bool diag){
    f32x4 s[2][4];
    #pragma unroll
    for (int mq = 0; mq < 2; ++mq)
      #pragma unroll
      for (int nk = 0; nk < 4; ++nk) s[mq][nk] = f32x4{0.f,0.f,0.f,0.f};
    #pragma unroll
    for (int nk = 0; nk < 4; ++nk){
      int krow = nk*16 + r16;
      #pragma unroll
      for (int dh = 0; dh < 2; ++dh){
        short8 kf = *(const short8*)&Kls[cur][krow * 64 + (((dh*4 + g) ^ (krow & 7)) << 3)];
        #pragma unroll
        for (int mq = 0; mq < 2; ++mq)
          s[mq][nk] = __builtin_amdgcn_mfma_f32_16x16x32_bf16(qf[mq][dh], kf, s[mq][nk], 0, 0, 0);
      }
    }
    #pragma unroll
    for (int mq = 0; mq < 2; ++mq){
      int qv = qw + mq*16 + g*4;
      #pragma unroll
      for (int nk = 0; nk < 4; ++nk){
        int kc = kt*64 + nk*16 + r16;
        #pragma unroll
        for (int j = 0; j < 4; ++j){
          float t = s[mq][nk][j];
          if (diag) t = (kc <= qv + j) ? t : -1e30f;
          float p = __builtin_amdgcn_exp2f(t);
          union { float f; unsigned u; } c; c.f = p;
          int row = mq*16 + g*4 + j, col = nk*16 + r16;
          Pw[(row << 6) + ((((col >> 3) ^ (row & 7)) << 3) | (col & 7))] =
              (unsigned short)((c.u + 0x8000u) >> 16);
        }
      }
    }
    asm volatile("" ::: "memory");
    short8 pf[2][2];
    #pragma unroll
    for (int mq = 0; mq < 2; ++mq){
      int prow = mq*16 + r16;
      #pragma unroll
      for (int ks = 0; ks < 2; ++ks)
        pf[mq][ks] = *(const short8*)&Pw[(prow << 6) + (((ks*4 + g) ^ (prow & 7)) << 3)];
      acc_l[mq] = __builtin_amdgcn_mfma_f32_16x16x32_bf16(pf[mq][0], ones, acc_l[mq], 0, 0, 0);
      acc_l[mq] = __builtin_amdgcn_mfma_f32_16x16x32_bf16(pf[mq][1], ones, acc_l[mq], 0, 0, 0);
    }
    #pragma unroll
    for (int ks = 0; ks < 2; ++ks){
      #pragma unroll
      for (int nd = 0; nd < 4; ++nd){
        int vrow = nd*16 + r16;
        short8 vf = *(const short8*)&Vls[cur][vrow * 64 + (((ks*4 + g) ^ (vrow & 7)) << 3)];
        #pragma unroll
        for (int mq = 0; mq < 2; ++mq)
          o[mq][nd] = __builtin_amdgcn_mfma_f32_16x16x32_bf16(pf[mq][ks], vf, o[mq][nd], 0, 0, 0);
      }
    }
  };

  int nkt = 2 * (qt + 1);
  stage(0, 0);
  __syncthreads();
  int cur = 0;
  for (int kt = 0; kt < nkt - 1; ++kt){
    stage(cur ^ 1, kt + 1);
    compute_tile(cur, kt, kt >= 2*qt);
    __syncthreads();
    cur ^= 1;
  }
  compute_tile(cur, nkt - 1, true);

  unsigned short* ob = attn_out + (size_t)b * Lc * Dc + h * HDc;
  #pragma unroll
  for (int mq = 0; mq < 2; ++mq){
    float inv[4];
    #pragma unroll
    for (int j = 0; j < 4; ++j) inv[j] = 1.0f / acc_l[mq][j];
    #pragma unroll
    for (int nd = 0; nd < 4; ++nd)
      #pragma unroll
      for (int j = 0; j < 4; ++j){
        int q2 = qw + mq*16 + g*4 + j;
        ob[(size_t)q2 * Dc + nd*16 + r16] = f2bf(o[mq][nd][j] * inv[j]);
      }
  }
}

// ---------- launch ----------
extern "C" void kernel_launch(void* const* d_in, const int* in_sizes, int n_in,
                              void* d_out, int out_size, void* d_ws, size_t ws_size,
                              hipStream_t stream){
  const float* x     = (const float*)d_in[0];
  const float* ln1_g = (const float*)d_in[2];
  const float* ln1_b = (const float*)d_in[3];
  const float* w_qkv = (const float*)d_in[4];
  const float* b_qkv = (const float*)d_in[5];
  const float* w_o   = (const float*)d_in[6];
  const float* b_o   = (const float*)d_in[7];
  const float* ln2_g = (const float*)d_in[8];
  const float* ln2_b = (const float*)d_in[9];
  const float* w1    = (const float*)d_in[10];
  const float* b1    = (const float*)d_in[11];
  const float* w2    = (const float*)d_in[12];
  const float* b2    = (const float*)d_in[13];

  char* ws = (char*)d_ws;
  size_t off = 0;
  auto alloc = [&](size_t bytes){ void* p = ws + off; off += (bytes + 255) & ~(size_t)255; return p; };
  unsigned short* wqkv_t = (unsigned short*)alloc((size_t)N3 * Dc * 2);
  unsigned short* wo_t   = (unsigned short*)alloc((size_t)Dc * Dc * 2);
  unsigned short* w1_t   = (unsigned short*)alloc((size_t)Ic * Dc * 2);
  unsigned short* w2_t   = (unsigned short*)alloc((size_t)Dc * Ic * 2);
  unsigned short* hbuf   = (unsigned short*)alloc((size_t)Mrows * Dc * 2);
  unsigned short* oattn  = (unsigned short*)alloc((size_t)Mrows * Dc * 2);   // bf16
  unsigned short* vtb    = (unsigned short*)alloc((size_t)Bc * Hc * HDc * Lc * 2);
  char*           big    = (char*)alloc((size_t)Mrows * Ic * 2);
  unsigned short* qkv    = (unsigned short*)big;
  unsigned short* attn_o = (unsigned short*)(big + (size_t)Mrows * N3 * 2);
  unsigned short* ff1    = (unsigned short*)big;

  dim3 tb(32, 8, 1);
  transpose_w<<<dim3(N3/32, Dc/32), tb, 0, stream>>>(w_qkv, wqkv_t, Dc, N3);
  transpose_w<<<dim3(Dc/32, Dc/32), tb, 0, stream>>>(w_o,   wo_t,   Dc, Dc);
  transpose_w<<<dim3(Ic/32, Dc/32), tb, 0, stream>>>(w1,    w1_t,   Dc, Ic);
  transpose_w<<<dim3(Dc/32, Ic/32), tb, 0, stream>>>(w2,    w2_t,   Ic, Dc);

  ln_kernel<<<dim3(Mrows), dim3(256), 0, stream>>>(x, ln1_g, ln1_b, hbuf);

  gemm8p<<<dim3(N3/256, Mrows/128), dim3(512), 0, stream>>>(hbuf, wqkv_t, b_qkv, qkv, Dc, N3);

  transpose_v<<<dim3(Lc/32, HDc/32, Bc*Hc), tb, 0, stream>>>(qkv, vtb);

  attn_kernel<<<dim3(Bc*Hc, Lc/128), dim3(256), 0, stream>>>(qkv, vtb, attn_o);

  gemm64<1><<<dim3(Dc/128, Mrows/64), dim3(512), 0, stream>>>(attn_o, wo_t, b_o, (const void*)x, (void*)oattn, Dc, Dc);

  ln_kernel_bf<<<dim3(Mrows), dim3(256), 0, stream>>>(oattn, ln2_g, ln2_b, hbuf);

  gemm8p<<<dim3(Ic/256, Mrows/128), dim3(512), 0, stream>>>(hbuf, w1_t, b1, ff1, Dc, Ic);

  gemm64<2><<<dim3(Dc/128, Mrows/64), dim3(512), 0, stream>>>(ff1, w2_t, b2, (const void*)oattn, d_out, Ic, Dc);
}

// Round 20
// 252.547 us; speedup vs baseline: 1.0924x; 1.0924x over previous
//
#include <hip/hip_runtime.h>
#include <stdint.h>

// ---------- types / helpers ----------
typedef __attribute__((ext_vector_type(8))) short short8;   // 8 x bf16 (4 VGPRs)
typedef __attribute__((ext_vector_type(4))) float f32x4;

typedef const void __attribute__((address_space(1)))* gas1_t;
typedef void __attribute__((address_space(3)))* las3_t;
#define GLL16(g, l) __builtin_amdgcn_global_load_lds((gas1_t)(const void*)(g), (las3_t)(void*)(l), 16, 0, 0)

__device__ __forceinline__ unsigned short f2bf(float x){
  union { float f; unsigned u; } c; c.f = x;
  return (unsigned short)((c.u + 0x7fffu + ((c.u >> 16) & 1u)) >> 16);
}
__device__ __forceinline__ float bf2f(unsigned short u){
  union { unsigned u; float f; } c; c.u = ((unsigned)u) << 16; return c.f;
}
__device__ __forceinline__ unsigned cvtpk(float lo, float hi){
  unsigned r;
  asm("v_cvt_pk_bf16_f32 %0, %1, %2" : "=v"(r) : "v"(lo), "v"(hi));
  return r;
}

__device__ __forceinline__ short8 pack_bf16x8(f32x4 a, f32x4 b){
  union { unsigned u[4]; short8 s8; } r;
  r.u[0] = cvtpk(a[0], a[1]);
  r.u[1] = cvtpk(a[2], a[3]);
  r.u[2] = cvtpk(b[0], b[1]);
  r.u[3] = cvtpk(b[2], b[3]);
  return r.s8;
}

constexpr int Bc = 4, Lc = 2048, Dc = 768, Hc = 12, HDc = 64, Ic = 3072;
constexpr int Mrows = Bc * Lc;        // 8192
constexpr int N3 = 3 * Dc;            // 2304

// ---------- weight transpose fp32[K][N] -> bf16[N][K] ----------
__global__ void transpose_w(const float* __restrict__ W, unsigned short* __restrict__ Wt, int K, int N){
  __shared__ float t[32][33];
  int n0 = blockIdx.x * 32, k0 = blockIdx.y * 32;
  int tx = threadIdx.x, ty = threadIdx.y;   // (32,8)
  #pragma unroll
  for (int j = 0; j < 4; ++j)
    t[ty + 8*j][tx] = W[(size_t)(k0 + ty + 8*j) * N + n0 + tx];
  __syncthreads();
  #pragma unroll
  for (int j = 0; j < 4; ++j)
    Wt[(size_t)(n0 + ty + 8*j) * K + k0 + tx] = f2bf(t[tx][ty + 8*j]);
}

// ---------- V transpose: vt[bh][d=64][L=2048] from qkv ----------
__global__ void transpose_v(const unsigned short* __restrict__ qkv, unsigned short* __restrict__ vt){
  __shared__ unsigned short t[32][33];
  int l0 = blockIdx.x * 32, d0 = blockIdx.y * 32;
  int bh = blockIdx.z; int b = bh / Hc, h = bh - b * Hc;
  int tx = threadIdx.x, ty = threadIdx.y;   // (32,8)
  const unsigned short* src = qkv + (size_t)b * Lc * N3 + h * 192 + 128;
  #pragma unroll
  for (int j = 0; j < 4; ++j)
    t[ty + 8*j][tx] = src[(size_t)(l0 + ty + 8*j) * N3 + d0 + tx];
  __syncthreads();
  unsigned short* dst = vt + (size_t)bh * 64 * Lc;
  #pragma unroll
  for (int j = 0; j < 4; ++j)
    dst[(size_t)(d0 + ty + 8*j) * Lc + l0 + tx] = t[tx][ty + 8*j];
}

// ---------- LayerNorm: fp32 row (768) -> bf16 row ----------
__global__ __launch_bounds__(256) void ln_kernel(const float* __restrict__ x, const float* __restrict__ g,
                                                 const float* __restrict__ bta, unsigned short* __restrict__ out){
  int row = blockIdx.x, tid = threadIdx.x;
  const float* xr = x + (size_t)row * 768;
  float v0 = xr[tid], v1 = xr[tid + 256], v2 = xr[tid + 512];
  float s = v0 + v1 + v2;
  float ss = v0*v0 + v1*v1 + v2*v2;
  #pragma unroll
  for (int o = 32; o > 0; o >>= 1){ s += __shfl_xor(s, o); ss += __shfl_xor(ss, o); }
  __shared__ float red[8];
  int w = tid >> 6;
  if ((tid & 63) == 0){ red[w] = s; red[4 + w] = ss; }
  __syncthreads();
  s  = red[0] + red[1] + red[2] + red[3];
  ss = red[4] + red[5] + red[6] + red[7];
  float mu  = s * (1.f / 768.f);
  float var = ss * (1.f / 768.f) - mu * mu;
  float rs  = rsqrtf(var + 1e-5f);
  unsigned short* orow = out + (size_t)row * 768;
  orow[tid]       = f2bf((v0 - mu) * rs * g[tid]       + bta[tid]);
  orow[tid + 256] = f2bf((v1 - mu) * rs * g[tid + 256] + bta[tid + 256]);
  orow[tid + 512] = f2bf((v2 - mu) * rs * g[tid + 512] + bta[tid + 512]);
}

// ---------- LayerNorm: bf16 row (768) -> bf16 row ----------
__global__ __launch_bounds__(256) void ln_kernel_bf(const unsigned short* __restrict__ x, const float* __restrict__ g,
                                                    const float* __restrict__ bta, unsigned short* __restrict__ out){
  int row = blockIdx.x, tid = threadIdx.x;
  const unsigned short* xr = x + (size_t)row * 768;
  float v0 = bf2f(xr[tid]), v1 = bf2f(xr[tid + 256]), v2 = bf2f(xr[tid + 512]);
  float s = v0 + v1 + v2;
  float ss = v0*v0 + v1*v1 + v2*v2;
  #pragma unroll
  for (int o = 32; o > 0; o >>= 1){ s += __shfl_xor(s, o); ss += __shfl_xor(ss, o); }
  __shared__ float red[8];
  int w = tid >> 6;
  if ((tid & 63) == 0){ red[w] = s; red[4 + w] = ss; }
  __syncthreads();
  s  = red[0] + red[1] + red[2] + red[3];
  ss = red[4] + red[5] + red[6] + red[7];
  float mu  = s * (1.f / 768.f);
  float var = ss * (1.f / 768.f) - mu * mu;
  float rs  = rsqrtf(var + 1e-5f);
  unsigned short* orow = out + (size_t)row * 768;
  orow[tid]       = f2bf((v0 - mu) * rs * g[tid]       + bta[tid]);
  orow[tid + 256] = f2bf((v1 - mu) * rs * g[tid + 256] + bta[tid + 256]);
  orow[tid + 512] = f2bf((v2 - mu) * rs * g[tid + 512] + bta[tid + 512]);
}

// ---------- wide GEMM: BM=128, BN=256, BK=64, 8 waves, per-wave 64x64 ----------
template<int MODE>
__global__ __launch_bounds__(512, 4) void gemm_wide(
    const unsigned short* __restrict__ A, const unsigned short* __restrict__ Bt,
    const float* __restrict__ bias, const float* __restrict__ res,
    void* __restrict__ outp, int Kdim, int Ndim)
{
  __shared__ __align__(16) unsigned short Als[128 * 64];      // 16 KB, single
  __shared__ __align__(16) unsigned short Bls[2][256 * 64];   // 64 KB, double
  int tid = threadIdx.x, w = tid >> 6, lane = tid & 63;
  int g = lane >> 4, r16 = lane & 15;
  int wm = w >> 2, wn = w & 3;                 // 2m x 4n waves, per-wave 64x64

  int nwg = gridDim.x * gridDim.y;
  int flat = blockIdx.y * gridDim.x + blockIdx.x;
  int cpx = nwg >> 3;
  int swz = (flat & 7) * cpx + (flat >> 3);
  int bx = swz % gridDim.x, by = swz / gridDim.x;
  int m0 = by * 128, n0 = bx * 256;

  f32x4 acc[4][4];
  #pragma unroll
  for (int m = 0; m < 4; ++m)
    #pragma unroll
    for (int n = 0; n < 4; ++n) acc[m][n] = f32x4{0.f, 0.f, 0.f, 0.f};

  int lrow = lane >> 3;                          // row within 8-row chunk
  int gsw8 = ((lane & 7) ^ lrow) * 8;            // inverse-swizzled source granule*8
  auto stageA = [&](int kt){                     // 2 GLL16/thread
    int k0 = kt * 64;
    #pragma unroll
    for (int i = 0; i < 2; ++i){
      int c = w * 2 + i;
      int row = c * 8 + lrow;
      GLL16(A + (size_t)(m0 + row) * Kdim + k0 + gsw8, &Als[c * 512]);
    }
  };
  auto stageB = [&](int buf, int kt){            // 4 GLL16/thread
    int k0 = kt * 64;
    #pragma unroll
    for (int i = 0; i < 4; ++i){
      int c = w * 4 + i;
      int row = c * 8 + lrow;
      GLL16(Bt + (size_t)(n0 + row) * Kdim + k0 + gsw8, &Bls[buf][c * 512]);
    }
  };

  int nk = Kdim >> 6;
  stageB(0, 0);
  int cur = 0;
  for (int kt = 0; kt < nk; ++kt){
    __builtin_amdgcn_s_barrier();
    stageA(kt);
    if (kt + 1 < nk){
      stageB(cur ^ 1, kt + 1);
      asm volatile("s_waitcnt vmcnt(4)" ::: "memory");  // A(kt)+B(kt) landed
    } else {
      asm volatile("s_waitcnt vmcnt(0)" ::: "memory");
    }
    __builtin_amdgcn_s_barrier();

    #pragma unroll
    for (int ks = 0; ks < 2; ++ks){
      short8 af[4], bfv[4];
      #pragma unroll
      for (int m = 0; m < 4; ++m){
        int r = wm * 64 + m * 16 + r16;
        af[m] = *(const short8*)&Als[r * 64 + (((ks*4 + g) ^ (r & 7)) << 3)];
      }
      #pragma unroll
      for (int n = 0; n < 4; ++n){
        int r = wn * 64 + n * 16 + r16;
        bfv[n] = *(const short8*)&Bls[cur][r * 64 + (((ks*4 + g) ^ (r & 7)) << 3)];
      }
      __builtin_amdgcn_s_setprio(1);
      #pragma unroll
      for (int m = 0; m < 4; ++m)
        #pragma unroll
        for (int n = 0; n < 4; ++n)
          acc[m][n] = __builtin_amdgcn_mfma_f32_16x16x32_bf16(af[m], bfv[n], acc[m][n], 0, 0, 0);
      __builtin_amdgcn_s_setprio(0);
    }
    cur ^= 1;
  }

  #pragma unroll
  for (int n = 0; n < 4; ++n){
    int col = n0 + wn * 64 + n * 16 + r16;
    float bv = bias[col];
    #pragma unroll
    for (int m = 0; m < 4; ++m){
      #pragma unroll
      for (int j = 0; j < 4; ++j){
        int rowg = m0 + wm * 64 + m * 16 + g * 4 + j;
        size_t idx = (size_t)rowg * Ndim + col;
        float v = acc[m][n][j] + bv;
        ((unsigned short*)outp)[idx] = f2bf(v);
      }
    }
  }
}

// ---------- small GEMM: BM=64, BN=128, BK=64, 8 waves (2m x 4n), per-wave 32x32 ----
template<int MODE>
__global__ __launch_bounds__(512, 6) void gemm64(
    const unsigned short* __restrict__ A, const unsigned short* __restrict__ Bt,
    const float* __restrict__ bias, const void* __restrict__ res,
    void* __restrict__ outp, int Kdim, int Ndim)
{
  __shared__ __align__(16) unsigned short Als[2][64 * 64];    // 16 KB
  __shared__ __align__(16) unsigned short Bls[2][128 * 64];   // 32 KB
  int tid = threadIdx.x, w = tid >> 6, lane = tid & 63;
  int g = lane >> 4, r16 = lane & 15;
  int wm = w >> 2, wn = w & 3;                 // 2m x 4n waves, per-wave 32x32

  int nwg = gridDim.x * gridDim.y;
  int flat = blockIdx.y * gridDim.x + blockIdx.x;
  int cpx = nwg >> 3;
  int swz = (flat & 7) * cpx + (flat >> 3);
  int bx = swz % gridDim.x, by = swz / gridDim.x;
  int m0 = by * 64, n0 = bx * 128;

  f32x4 acc[2][2];
  #pragma unroll
  for (int m = 0; m < 2; ++m)
    #pragma unroll
    for (int n = 0; n < 2; ++n) acc[m][n] = f32x4{0.f, 0.f, 0.f, 0.f};

  int lrow = lane >> 3;                          // row within 8-row chunk
  int gsw8 = ((lane & 7) ^ lrow) * 8;            // inverse-swizzled source granule*8
  auto stage = [&](int buf, int kt){             // 3 GLL16/thread (1 A + 2 B)
    int k0 = kt * 64;
    {
      int c = w;                                 // A: 8 chunks of 8 rows
      int row = c * 8 + lrow;
      GLL16(A + (size_t)(m0 + row) * Kdim + k0 + gsw8, &Als[buf][c * 512]);
    }
    #pragma unroll
    for (int i = 0; i < 2; ++i){                 // B: 16 chunks of 8 rows
      int c = w * 2 + i;
      int row = c * 8 + lrow;
      GLL16(Bt + (size_t)(n0 + row) * Kdim + k0 + gsw8, &Bls[buf][c * 512]);
    }
  };

  int nk = Kdim >> 6;
  stage(0, 0);                                   // 3 loads in flight
  int cur = 0;
  for (int kt = 0; kt < nk; ++kt){
    __builtin_amdgcn_s_barrier();                // buf cur^1 free
    if (kt + 1 < nk){
      stage(cur ^ 1, kt + 1);                    // +3 loads (6 in flight)
      asm volatile("s_waitcnt vmcnt(3)" ::: "memory");  // oldest 3 (tile kt) landed
    } else {
      asm volatile("s_waitcnt vmcnt(0)" ::: "memory");
    }
    __builtin_amdgcn_s_barrier();                // tile kt visible

    #pragma unroll
    for (int ks = 0; ks < 2; ++ks){
      short8 af[2], bfv[2];
      #pragma unroll
      for (int m = 0; m < 2; ++m){
        int r = wm * 32 + m * 16 + r16;
        af[m] = *(const short8*)&Als[cur][r * 64 + (((ks*4 + g) ^ (r & 7)) << 3)];
      }
      #pragma unroll
      for (int n = 0; n < 2; ++n){
        int r = wn * 32 + n * 16 + r16;
        bfv[n] = *(const short8*)&Bls[cur][r * 64 + (((ks*4 + g) ^ (r & 7)) << 3)];
      }
      #pragma unroll
      for (int m = 0; m < 2; ++m)
        #pragma unroll
        for (int n = 0; n < 2; ++n)
          acc[m][n] = __builtin_amdgcn_mfma_f32_16x16x32_bf16(af[m], bfv[n], acc[m][n], 0, 0, 0);
    }
    cur ^= 1;
  }

  #pragma unroll
  for (int n = 0; n < 2; ++n){
    int col = n0 + wn * 32 + n * 16 + r16;
    float bv = bias[col];
    #pragma unroll
    for (int m = 0; m < 2; ++m){
      #pragma unroll
      for (int j = 0; j < 4; ++j){
        int rowg = m0 + wm * 32 + m * 16 + g * 4 + j;
        size_t idx = (size_t)rowg * Ndim + col;
        float v = acc[m][n][j] + bv;
        if (MODE == 1){
          ((unsigned short*)outp)[idx] = f2bf(v + ((const float*)res)[idx]);
        } else {
          float ge = 0.5f * v * (1.0f + erff(v * 0.70710678118f));
          ((float*)outp)[idx] = bf2f(((const unsigned short*)res)[idx]) + ge;
        }
      }
    }
  }
}

// ---------- flash attention (causal, scores/64), mq=2: 32 q-rows/wave ----------
// R15-proven structure (f32 P in LDS + pack_bf16x8 read, 64KB LDS) with two
// individually-proven deltas from R18: (1) Q pre-scaled by log2(e)/64 at load,
// (2) l via MFMA(P, ones) -- kills 32 adds/tile + the final shuffle reduction.
__global__ __launch_bounds__(256, 2) void attn_kernel(const unsigned short* __restrict__ qkv,
                                                      const unsigned short* __restrict__ vt,
                                                      unsigned short* __restrict__ attn_out){
  int qt = 15 - blockIdx.y;            // big blocks dispatch first
  int bh = blockIdx.x;
  int b = bh / Hc, h = bh - b * Hc;
  int tid = threadIdx.x, w = tid >> 6, lane = tid & 63;
  int g = lane >> 4, r16 = lane & 15;
  const unsigned short* base  = qkv + (size_t)b * Lc * N3 + h * 192;
  const unsigned short* vbase = vt + (size_t)bh * 64 * Lc;

  __shared__ __align__(16) unsigned short Kls[2][64 * 64];   // 16 KB
  __shared__ __align__(16) unsigned short Vls[2][64 * 64];   // 16 KB
  __shared__ __align__(16) float Pls[4][32 * 64];            // 32 KB

  constexpr float SM_SCALE = 0.022542110013890052f;   // log2(e)/64

  int qw = qt * 128 + w * 32;          // wave's 32 q rows
  short8 qf[2][2];
  #pragma unroll
  for (int mq = 0; mq < 2; ++mq)
    #pragma unroll
    for (int dh = 0; dh < 2; ++dh){
      short8 v = *(const short8*)(base + (size_t)(qw + mq*16 + r16) * N3 + dh*32 + g*8);
      union { unsigned u[4]; short8 s8; } r;
      #pragma unroll
      for (int i = 0; i < 4; ++i){
        float lo = bf2f((unsigned short)v[2*i])     * SM_SCALE;
        float hi = bf2f((unsigned short)v[2*i + 1]) * SM_SCALE;
        r.u[i] = cvtpk(lo, hi);
      }
      qf[mq][dh] = r.s8;
    }

  short8 ones;
  #pragma unroll
  for (int i = 0; i < 8; ++i) ones[i] = (short)0x3F80;   // bf16 1.0

  f32x4 o[2][4];
  f32x4 acc_l[2];
  #pragma unroll
  for (int mq = 0; mq < 2; ++mq){
    #pragma unroll
    for (int nd = 0; nd < 4; ++nd) o[mq][nd] = f32x4{0.f, 0.f, 0.f, 0.f};
    acc_l[mq] = f32x4{0.f, 0.f, 0.f, 0.f};
  }

  float* Pw = &Pls[w][0];

  int lrow = lane >> 3, csw8 = ((lane & 7) ^ lrow) * 8;
  auto stage = [&](int buf, int kt){
    #pragma unroll
    for (int i = 0; i < 2; ++i){
      int r0 = (w * 2 + i) * 8;
      int row = r0 + lrow;
      GLL16(base  + (size_t)(kt*64 + row) * N3 + 64 + csw8, &Kls[buf][r0 * 64]);
      GLL16(vbase + (size_t)row * Lc + kt*64 + csw8,        &Vls[buf][r0 * 64]);
    }
  };

  auto compute_tile = [&](int cur, int kt, bool diag){
    // QK^T (Q pre-scaled): S[32q x 64k] per wave, already in exp2 units
    f32x4 s[2][4];
    #pragma unroll
    for (int mq = 0; mq < 2; ++mq)
      #pragma unroll
      for (int nk = 0; nk < 4; ++nk) s[mq][nk] = f32x4{0.f,0.f,0.f,0.f};
    #pragma unroll
    for (int nk = 0; nk < 4; ++nk){
      int krow = nk*16 + r16;
      #pragma unroll
      for (int dh = 0; dh < 2; ++dh){
        short8 kf = *(const short8*)&Kls[cur][krow * 64 + (((dh*4 + g) ^ (krow & 7)) << 3)];
        #pragma unroll
        for (int mq = 0; mq < 2; ++mq)
          s[mq][nk] = __builtin_amdgcn_mfma_f32_16x16x32_bf16(qf[mq][dh], kf, s[mq][nk], 0, 0, 0);
      }
    }
    // softmax-lite: p = exp2(s), fixed max; P -> per-wave f32 LDS (swizzled)
    #pragma unroll
    for (int mq = 0; mq < 2; ++mq){
      int qv = qw + mq*16 + g*4;
      #pragma unroll
      for (int nk = 0; nk < 4; ++nk){
        int kc = kt*64 + nk*16 + r16;
        #pragma unroll
        for (int j = 0; j < 4; ++j){
          float t = s[mq][nk][j];
          if (diag) t = (kc <= qv + j) ? t : -1e30f;
          float p = __builtin_amdgcn_exp2f(t);
          int row = mq*16 + g*4 + j, col = nk*16 + r16;
          Pw[(row << 6) + ((((col >> 2) ^ (row & 7)) << 2) | (col & 3))] = p;
        }
      }
    }
    asm volatile("" ::: "memory");
    // PV: O[32q x 64d] += P[32x64] @ V^T[64d x 64k]^T ; l via MFMA(P, ones)
    short8 pf[2][2];
    #pragma unroll
    for (int mq = 0; mq < 2; ++mq){
      int prow = mq*16 + r16;
      #pragma unroll
      for (int ks = 0; ks < 2; ++ks){
        int gr0 = (ks*8 + g*2) ^ (prow & 7);
        int gr1 = (ks*8 + g*2 + 1) ^ (prow & 7);
        f32x4 pa = *(const f32x4*)&Pw[(prow << 6) + (gr0 << 2)];
        f32x4 pb = *(const f32x4*)&Pw[(prow << 6) + (gr1 << 2)];
        pf[mq][ks] = pack_bf16x8(pa, pb);
      }
      acc_l[mq] = __builtin_amdgcn_mfma_f32_16x16x32_bf16(pf[mq][0], ones, acc_l[mq], 0, 0, 0);
      acc_l[mq] = __builtin_amdgcn_mfma_f32_16x16x32_bf16(pf[mq][1], ones, acc_l[mq], 0, 0, 0);
    }
    #pragma unroll
    for (int ks = 0; ks < 2; ++ks){
      #pragma unroll
      for (int nd = 0; nd < 4; ++nd){
        int vrow = nd*16 + r16;
        short8 vf = *(const short8*)&Vls[cur][vrow * 64 + (((ks*4 + g) ^ (vrow & 7)) << 3)];
        #pragma unroll
        for (int mq = 0; mq < 2; ++mq)
          o[mq][nd] = __builtin_amdgcn_mfma_f32_16x16x32_bf16(pf[mq][ks], vf, o[mq][nd], 0, 0, 0);
      }
    }
  };

  int nkt = 2 * (qt + 1);
  stage(0, 0);
  __syncthreads();
  int cur = 0;
  for (int kt = 0; kt < nkt - 1; ++kt){
    stage(cur ^ 1, kt + 1);
    compute_tile(cur, kt, kt >= 2*qt);
    __syncthreads();
    cur ^= 1;
  }
  compute_tile(cur, nkt - 1, true);

  unsigned short* ob = attn_out + (size_t)b * Lc * Dc + h * HDc;
  #pragma unroll
  for (int mq = 0; mq < 2; ++mq){
    float inv[4];
    #pragma unroll
    for (int j = 0; j < 4; ++j) inv[j] = 1.0f / acc_l[mq][j];
    #pragma unroll
    for (int nd = 0; nd < 4; ++nd)
      #pragma unroll
      for (int j = 0; j < 4; ++j){
        int q2 = qw + mq*16 + g*4 + j;
        ob[(size_t)q2 * Dc + nd*16 + r16] = f2bf(o[mq][nd][j] * inv[j]);
      }
  }
}

// ---------- launch ----------
extern "C" void kernel_launch(void* const* d_in, const int* in_sizes, int n_in,
                              void* d_out, int out_size, void* d_ws, size_t ws_size,
                              hipStream_t stream){
  const float* x     = (const float*)d_in[0];
  const float* ln1_g = (const float*)d_in[2];
  const float* ln1_b = (const float*)d_in[3];
  const float* w_qkv = (const float*)d_in[4];
  const float* b_qkv = (const float*)d_in[5];
  const float* w_o   = (const float*)d_in[6];
  const float* b_o   = (const float*)d_in[7];
  const float* ln2_g = (const float*)d_in[8];
  const float* ln2_b = (const float*)d_in[9];
  const float* w1    = (const float*)d_in[10];
  const float* b1    = (const float*)d_in[11];
  const float* w2    = (const float*)d_in[12];
  const float* b2    = (const float*)d_in[13];

  char* ws = (char*)d_ws;
  size_t off = 0;
  auto alloc = [&](size_t bytes){ void* p = ws + off; off += (bytes + 255) & ~(size_t)255; return p; };
  unsigned short* wqkv_t = (unsigned short*)alloc((size_t)N3 * Dc * 2);
  unsigned short* wo_t   = (unsigned short*)alloc((size_t)Dc * Dc * 2);
  unsigned short* w1_t   = (unsigned short*)alloc((size_t)Ic * Dc * 2);
  unsigned short* w2_t   = (unsigned short*)alloc((size_t)Dc * Ic * 2);
  unsigned short* hbuf   = (unsigned short*)alloc((size_t)Mrows * Dc * 2);
  unsigned short* oattn  = (unsigned short*)alloc((size_t)Mrows * Dc * 2);   // bf16
  unsigned short* vtb    = (unsigned short*)alloc((size_t)Bc * Hc * HDc * Lc * 2);
  char*           big    = (char*)alloc((size_t)Mrows * Ic * 2);
  unsigned short* qkv    = (unsigned short*)big;
  unsigned short* attn_o = (unsigned short*)(big + (size_t)Mrows * N3 * 2);
  unsigned short* ff1    = (unsigned short*)big;

  dim3 tb(32, 8, 1);
  transpose_w<<<dim3(N3/32, Dc/32), tb, 0, stream>>>(w_qkv, wqkv_t, Dc, N3);
  transpose_w<<<dim3(Dc/32, Dc/32), tb, 0, stream>>>(w_o,   wo_t,   Dc, Dc);
  transpose_w<<<dim3(Ic/32, Dc/32), tb, 0, stream>>>(w1,    w1_t,   Dc, Ic);
  transpose_w<<<dim3(Dc/32, Ic/32), tb, 0, stream>>>(w2,    w2_t,   Ic, Dc);

  ln_kernel<<<dim3(Mrows), dim3(256), 0, stream>>>(x, ln1_g, ln1_b, hbuf);

  gemm_wide<0><<<dim3(N3/256, Mrows/128), dim3(512), 0, stream>>>(hbuf, wqkv_t, b_qkv, nullptr, (void*)qkv, Dc, N3);

  transpose_v<<<dim3(Lc/32, HDc/32, Bc*Hc), tb, 0, stream>>>(qkv, vtb);

  attn_kernel<<<dim3(Bc*Hc, Lc/128), dim3(256), 0, stream>>>(qkv, vtb, attn_o);

  gemm64<1><<<dim3(Dc/128, Mrows/64), dim3(512), 0, stream>>>(attn_o, wo_t, b_o, (const void*)x, (void*)oattn, Dc, Dc);

  ln_kernel_bf<<<dim3(Mrows), dim3(256), 0, stream>>>(oattn, ln2_g, ln2_b, hbuf);

  gemm_wide<0><<<dim3(Ic/256, Mrows/128), dim3(512), 0, stream>>>(hbuf, w1_t, b1, nullptr, (void*)ff1, Dc, Ic);

  gemm64<2><<<dim3(Dc/128, Mrows/64), dim3(512), 0, stream>>>(ff1, w2_t, b2, (const void*)oattn, d_out, Ic, Dc);
}